// Round 13
// baseline (161.301 us; speedup 1.0000x reference)
//
#include <hip/hip_runtime.h>
#include <stdint.h>

typedef _Float16 f16;
typedef __attribute__((ext_vector_type(8))) _Float16 f16x8;
typedef __attribute__((ext_vector_type(4))) float f32x4;
typedef __attribute__((ext_vector_type(2))) unsigned int u32x2;
typedef __attribute__((ext_vector_type(4))) unsigned int u32x4;
typedef decltype(__builtin_amdgcn_cvt_pkrtz(0.f, 0.f)) h2_t;

#define S_LEN 2048
#define BATCH 8
#define D_IN  1024
#define DHALF 512

__device__ __forceinline__ unsigned lds_off(const void* p) {
  return (unsigned)(size_t)p;
}

// async global->LDS DMA, 16B per lane (dest = wave-uniform base + lane*16 by HW)
__device__ __forceinline__ void dma16(const void* g, void* lds_uniform) {
  __builtin_amdgcn_global_load_lds(
      (const __attribute__((address_space(1))) void*)g,
      (__attribute__((address_space(3))) void*)lds_uniform, 16, 0, 0);
}

// ---------------------------------------------------------------------------
// W f32 -> f16 preconvert (one-shot, ~3MB): out[z] = (f16)W[z], layout [n][k].
// ---------------------------------------------------------------------------
__global__ __launch_bounds__(256) void wcvt_kernel(
    const float* __restrict__ Wq, const float* __restrict__ Wk, const float* __restrict__ Wv,
    f16* __restrict__ out)
{
  const int z = blockIdx.y;
  const float* W = (z == 0) ? Wq : (z == 1) ? Wk : Wv;
  const int idx = (blockIdx.x * 256 + threadIdx.x) * 8;
  f32x4 a = *(const f32x4*)(W + idx);
  f32x4 b = *(const f32x4*)(W + idx + 4);
  union { h2_t h2[4]; f16x8 v; } u;
  u.h2[0] = __builtin_amdgcn_cvt_pkrtz(a.x, a.y);
  u.h2[1] = __builtin_amdgcn_cvt_pkrtz(a.z, a.w);
  u.h2[2] = __builtin_amdgcn_cvt_pkrtz(b.x, b.y);
  u.h2[3] = __builtin_amdgcn_cvt_pkrtz(b.z, b.w);
  *(f16x8*)(out + (size_t)z * (DHALF * D_IN) + idx) = u.v;
}

// ---------------------------------------------------------------------------
// Projection v6. out[s,b,e] = sum_d X[s,b,d]*W[e,d] + bias[e], fp16.
// BM=128 x BN=512, 8 waves, wave-tile 128m x 64n. Changes vs v4 (r10 champ):
//  * B fragments loaded GLOBAL->REG directly (W fp16 is L2-resident, 1MB/z;
//    lane -> n-row w*64+nf*16+rl, 16B at k-byte g*16 -- natively MFMA-shaped).
//    NO LDS transit for B: per-kc LDS pipe drops ~3.1k -> ~1.6k cy, and the
//    serially-exposed B DMA drain (r10's vmcnt(4)) disappears.
//  * bf double-buffered at ks granularity (bfE/bfO, 32 regs); compiler SSA
//    vmcnt covers each set under the other set's MFMA.
// A path identical to r10: once-chip-wide 256B NT runs -> reg -> cvt f16 ->
// XOR-swizzled LDS [128][128B], dbuf, ONE raw barrier per kc64. LDS 32KB.
// ---------------------------------------------------------------------------
__global__ __launch_bounds__(512, 1) void proj_kernel(
    const float* __restrict__ Xq, const float* __restrict__ Xk, const float* __restrict__ Xv,
    const f16* __restrict__ Wf16,
    const float* __restrict__ bq, const float* __restrict__ bk, const float* __restrict__ bv,
    f16* __restrict__ oq, f16* __restrict__ ok, f16* __restrict__ ov)
{
  const int z = blockIdx.z;
  const float* X    = (z == 0) ? Xq : (z == 1) ? Xk : Xv;
  const f16*   W    = Wf16 + (size_t)z * (DHALF * D_IN);
  const float* bias = (z == 0) ? bq : (z == 1) ? bk : bv;
  f16* out          = (z == 0) ? oq : (z == 1) ? ok : ov;

  const int m0 = blockIdx.x * 128;
  const int tid = threadIdx.x;
  const int lane = tid & 63;
  const int w = tid >> 6;               // wave 0..7 = n-column group (64 cols)
  const int rl = lane & 15, g = lane >> 4;

  __shared__ char Ab[2][16384];         // [128 rows][128B k] f16, XOR-swizzled

  f32x4 acc[8][4];
#pragma unroll
  for (int i = 0; i < 8; i++)
#pragma unroll
    for (int j = 0; j < 4; j++) acc[i][j] = (f32x4){0.f, 0.f, 0.f, 0.f};

  // A-load geometry (r10): instr i covers rows [w*16+i*4,+4), 256B run per row
  const int arow0 = w * 16 + (lane >> 4);
  const char* gA = (const char*)X + (size_t)(m0 + arow0) * (D_IN * 4) + (lane & 15) * 16;
  const unsigned awkb = (unsigned)(lane & 15) * 8;

  // B fragment base: lane -> n-row (w*64 + rl), k-byte g*16; frag (nf,kc,ks):
  //   gB + nf*16*2048 + kc*128 + ks*64
  const char* gB = (const char*)W + (size_t)(w * 64 + rl) * (D_IN * 2) + g * 16;

  f32x4 aS[4];
  f16x8 bfE[4], bfO[4];

#define LOAD_A(KC) {                                                          \
  _Pragma("unroll")                                                           \
  for (int i = 0; i < 4; i++)                                                 \
    aS[i] = __builtin_nontemporal_load(                                       \
        (const f32x4*)(gA + (size_t)i * 4 * (D_IN * 4) + (size_t)(KC) * 256)); }

#define WRITE_A(BUF) {                                                        \
  _Pragma("unroll")                                                           \
  for (int i = 0; i < 4; i++) {                                               \
    int row = arow0 + i * 4;                                                  \
    union { h2_t h[2]; u32x2 u; } d;                                          \
    d.h[0] = __builtin_amdgcn_cvt_pkrtz(aS[i].x, aS[i].y);                    \
    d.h[1] = __builtin_amdgcn_cvt_pkrtz(aS[i].z, aS[i].w);                    \
    *(u32x2*)(&Ab[BUF][0] + (unsigned)row * 128 +                             \
              (awkb ^ (((unsigned)(row & 7)) << 4))) = d.u;                   \
  } }

#define LOAD_BF(DST, KC, KS) {                                                \
  _Pragma("unroll")                                                           \
  for (int nf = 0; nf < 4; nf++)                                              \
    DST[nf] = *(const f16x8*)(gB + (size_t)nf * 16 * (D_IN * 2) +             \
                              (KC) * 128 + (KS) * 64); }

#define KSTEP(BUF, KS, BF) {                                                  \
  _Pragma("unroll")                                                           \
  for (int m = 0; m < 8; m++) {                                               \
    unsigned arow = (unsigned)(m * 16 + rl);                                  \
    f16x8 af = *(const f16x8*)(&Ab[BUF][0] + arow * 128 +                     \
               ((unsigned)((KS) * 64 + g * 16) ^ (((unsigned)(rl & 7)) << 4))); \
    _Pragma("unroll")                                                         \
    for (int nf = 0; nf < 4; nf++)                                            \
      acc[m][nf] = __builtin_amdgcn_mfma_f32_16x16x32_f16(                    \
          af, BF[nf], acc[m][nf], 0, 0, 0);                                   \
  } }

  // prologue: Ab[0] staged; A(1) + bfE(0,0) in flight
  LOAD_A(0);
  WRITE_A(0);                 // compiler waits the 4 A-loads (SSA)
  LOAD_BF(bfE, 0, 0);
  LOAD_A(1);
  asm volatile("s_waitcnt lgkmcnt(0)" ::: "memory");
  __builtin_amdgcn_s_barrier();                        // Ab[0] visible
  __builtin_amdgcn_sched_barrier(0);

  for (int kc = 0; kc < 16; ++kc) {
    const int cur = kc & 1;
    LOAD_BF(bfO, kc, 1);                // flies under KSTEP(ks0)
    KSTEP(cur, 0, bfE);                 // compiler vmcnt-waits bfE at first use
    if (kc < 15) { LOAD_BF(bfE, kc + 1, 0); }  // flies under KSTEP(ks1)
    KSTEP(cur, 1, bfO);
    if (kc < 15) {
      WRITE_A(cur ^ 1);                 // waits aS (A(kc+1) loads) via SSA
      asm volatile("s_waitcnt lgkmcnt(0)" ::: "memory");
      __builtin_amdgcn_s_barrier();     // Ab(kc+1) visible to all waves
      if (kc < 14) { LOAD_A(kc + 2); }
      __builtin_amdgcn_sched_barrier(0);
    }
  }
#undef LOAD_A
#undef WRITE_A
#undef LOAD_BF
#undef KSTEP

  // epilogue: + bias, cast fp16; C/D: col = lane&15, row = (lane>>4)*4 + r
#pragma unroll
  for (int m = 0; m < 8; m++) {
    const int row = m0 + m * 16 + g * 4;
#pragma unroll
    for (int nf = 0; nf < 4; nf++) {
      const int col = w * 64 + nf * 16 + rl;
      const float bb = bias[col];
#pragma unroll
      for (int r = 0; r < 4; r++)
        out[(size_t)(row + r) * DHALF + col] = (f16)(acc[m][nf][r] + bb);
    }
  }
}

// ---------------------------------------------------------------------------
// Batched GEMM-TN v2 (r11, unchanged): all staging via global_load_lds with
// pre-swizzled sources; triple buffer, counted vmcnt depth-2.
// ---------------------------------------------------------------------------
template <int EPI, int MI>
__global__ __launch_bounds__(256, 3) void gemm_tn2_kernel(
    const f16* __restrict__ A, long batchA, int lda,
    const f16* __restrict__ Bm, long batchB, int ldb,
    int Ksize,
    const int* __restrict__ mask,
    float* __restrict__ out, long batchOut, int ldo)
{
  constexpr int BM  = MI * 32;
  constexpr int NA  = BM / 64;
  constexpr int ASZ = BM * 64;
  constexpr int SSZ = ASZ + 8192;

  const int bz = blockIdx.z;
  const int n0 = blockIdx.x * 128;
  const int m0 = blockIdx.y * BM;
  const char* Abase = (const char*)(A + (size_t)bz * batchA);
  const char* Bbase = (const char*)(Bm + (size_t)bz * batchB);

  const int tid = threadIdx.x, lane = tid & 63, wave = tid >> 6;
  const int wr = wave >> 1, wc = wave & 1;
  const int g = lane >> 4, rl = lane & 15;

  __shared__ char Buf[3][SSZ];

  f32x4 acc[MI][4];
#pragma unroll
  for (int i = 0; i < MI; i++)
#pragma unroll
    for (int j = 0; j < 4; j++) acc[i][j] = (f32x4){0.f, 0.f, 0.f, 0.f};

  const char* gAsrc[NA];
  unsigned    ldsA[NA];
#pragma unroll
  for (int i = 0; i < NA; i++) {
    int row = wave * (BM / 4) + i * 16 + (lane >> 2);
    unsigned kbyte = (((unsigned)(lane & 3)) * 16) ^ ((((unsigned)lane >> 3) & 3u) << 4);
    gAsrc[i] = Abase + (size_t)(m0 + row) * lda * 2 + kbyte;
    ldsA[i]  = (unsigned)(wave * (BM / 4) + i * 16) * 64;
  }
  const char* gBsrc[2];
  unsigned    ldsB[2];
#pragma unroll
  for (int i = 0; i < 2; i++) {
    int nb   = wave * 2 + i;
    int phys = lane >> 3;
    int kb   = (phys & 3) * 2 + (phys >> 2);
    int kk   = kb * 4 + ((lane >> 1) & 3);
    int nn   = nb * 16 + (lane & 1) * 8;
    gBsrc[i] = Bbase + (size_t)kk * ldb * 2 + (size_t)(n0 + nn) * 2;
    ldsB[i]  = (unsigned)(ASZ + nb * 1024);
  }

#define ISSUE(BUF, STEP) {                                                    \
  _Pragma("unroll")                                                           \
  for (int i = 0; i < NA; i++)                                                \
    dma16(gAsrc[i] + (size_t)(STEP) * 64, &Buf[BUF][0] + ldsA[i]);            \
  _Pragma("unroll")                                                           \
  for (int i = 0; i < 2; i++)                                                 \
    dma16(gBsrc[i] + (size_t)(STEP) * 32 * ldb * 2, &Buf[BUF][0] + ldsB[i]); }

#define COMPUTE(BUF) {                                                        \
  f16x8 af[MI];                                                               \
  _Pragma("unroll")                                                           \
  for (int i = 0; i < MI; i++) {                                              \
    unsigned row  = (unsigned)(wr * (MI * 16) + i * 16 + rl);                 \
    unsigned byte = ((unsigned)(g * 16)) ^ ((((unsigned)rl >> 1) & 3u) << 4); \
    af[i] = *(const f16x8*)(&Buf[BUF][0] + row * 64 + byte);                  \
  }                                                                           \
  f16x8 bf[4];                                                                \
  _Pragma("unroll")                                                           \
  for (int j = 0; j < 4; j++) {                                               \
    unsigned addr = lds_off(&Buf[BUF][0]) + (unsigned)ASZ +                   \
                    (unsigned)((wc * 4 + j) * 1024) + (unsigned)lane * 8u;    \
    u32x2 lo, hi;                                                             \
    asm volatile("ds_read_b64_tr_b16 %0, %1" : "=v"(lo) : "v"(addr));         \
    asm volatile("ds_read_b64_tr_b16 %0, %1 offset:512" : "=v"(hi) : "v"(addr)); \
    union { u32x4 u; f16x8 h; } cc;                                           \
    cc.u = (u32x4){lo.x, lo.y, hi.x, hi.y};                                   \
    bf[j] = cc.h;                                                             \
  }                                                                           \
  asm volatile("s_waitcnt lgkmcnt(0)" ::: "memory");                          \
  __builtin_amdgcn_sched_barrier(0);                                          \
  _Pragma("unroll")                                                           \
  for (int i = 0; i < MI; i++)                                                \
    _Pragma("unroll")                                                         \
    for (int j = 0; j < 4; j++)                                               \
      acc[i][j] = __builtin_amdgcn_mfma_f32_16x16x32_f16(af[i], bf[j], acc[i][j], 0, 0, 0); }

  const int NK = Ksize >> 5;
  ISSUE(0, 0);
  ISSUE(1, 1);

  int cb = 0, ib = 2;
  for (int k = 0; k < NK; ++k) {
    if (k + 1 < NK) {
      if (MI == 2) { asm volatile("s_waitcnt vmcnt(3)" ::: "memory"); }
      else         { asm volatile("s_waitcnt vmcnt(4)" ::: "memory"); }
    } else {
      asm volatile("s_waitcnt vmcnt(0)" ::: "memory");
    }
    __builtin_amdgcn_s_barrier();
    __builtin_amdgcn_sched_barrier(0);
    if (k + 2 < NK) {
      ISSUE(ib, k + 2);
      ib = (ib == 2) ? 0 : ib + 1;
    }
    COMPUTE(cb);
    cb = (cb == 2) ? 0 : cb + 1;
  }
#undef ISSUE
#undef COMPUTE

  float* ob = out + (size_t)bz * batchOut;
#pragma unroll
  for (int i = 0; i < MI; i++) {
    const int row = m0 + wr * (MI * 16) + i * 16 + g * 4;
#pragma unroll
    for (int j = 0; j < 4; j++) {
      const int col = n0 + wc * 64 + j * 16 + rl;
#pragma unroll
      for (int r = 0; r < 4; r++) {
        float val = acc[i][j][r];
        if (EPI == 0) {
          if (mask[(row + r) * DHALF + col] != 0) val = -1e30f;
        }
        ob[(size_t)(row + r) * ldo + col] = val;
      }
    }
  }
}

// ---------------------------------------------------------------------------
// Row softmax over e (512) for 4096 rows; one wave per row; fp16 output.
// ---------------------------------------------------------------------------
__global__ __launch_bounds__(256) void softmax_kernel(
    const float* __restrict__ logits, f16* __restrict__ P)
{
  const int row  = blockIdx.x * 4 + (threadIdx.x >> 6);
  const int lane = threadIdx.x & 63;
  const float* rp = logits + (size_t)row * DHALF + lane * 8;
  f32x4 x0 = *(const f32x4*)rp;
  f32x4 x1 = *(const f32x4*)(rp + 4);

  float m = fmaxf(fmaxf(fmaxf(x0.x, x0.y), fmaxf(x0.z, x0.w)),
                  fmaxf(fmaxf(x1.x, x1.y), fmaxf(x1.z, x1.w)));
#pragma unroll
  for (int off = 32; off > 0; off >>= 1) m = fmaxf(m, __shfl_xor(m, off, 64));

  float e0 = __expf(x0.x - m), e1 = __expf(x0.y - m);
  float e2 = __expf(x0.z - m), e3 = __expf(x0.w - m);
  float e4 = __expf(x1.x - m), e5 = __expf(x1.y - m);
  float e6 = __expf(x1.z - m), e7 = __expf(x1.w - m);
  float s = ((e0 + e1) + (e2 + e3)) + ((e4 + e5) + (e6 + e7));
#pragma unroll
  for (int off = 32; off > 0; off >>= 1) s += __shfl_xor(s, off, 64);
  const float inv = 1.0f / s;

  union { h2_t h2[4]; f16x8 v; } o;
  o.h2[0] = __builtin_amdgcn_cvt_pkrtz(e0 * inv, e1 * inv);
  o.h2[1] = __builtin_amdgcn_cvt_pkrtz(e2 * inv, e3 * inv);
  o.h2[2] = __builtin_amdgcn_cvt_pkrtz(e4 * inv, e5 * inv);
  o.h2[3] = __builtin_amdgcn_cvt_pkrtz(e6 * inv, e7 * inv);
  *(f16x8*)(P + (size_t)row * DHALF + lane * 8) = o.v;
}

// ---------------------------------------------------------------------------
extern "C" void kernel_launch(void* const* d_in, const int* in_sizes, int n_in,
                              void* d_out, int out_size, void* d_ws, size_t ws_size,
                              hipStream_t stream) {
  const float* q    = (const float*)d_in[0];
  const float* k    = (const float*)d_in[1];
  const float* v    = (const float*)d_in[2];
  const int*   mask = (const int*)d_in[3];
  const float* Wq   = (const float*)d_in[4];
  const float* bq   = (const float*)d_in[5];
  const float* Wk   = (const float*)d_in[6];
  const float* bk   = (const float*)d_in[7];
  const float* Wv   = (const float*)d_in[8];
  const float* bv   = (const float*)d_in[9];

  char* ws = (char*)d_ws;
  f16*   qt     = (f16*)(ws);                                  // 16 MB
  f16*   kt     = (f16*)(ws + 16777216);                       // 16 MB
  f16*   vt     = (f16*)(ws + 2 * 16777216);                   // 16 MB
  float* logits = (float*)(ws + 3 * 16777216);                 // 8 MB
  f16*   P      = (f16*)(ws + 3 * 16777216 + 8388608);         // 4 MB
  // Wf16 (3 MB) overlaps the logits region (consumed before QK writes logits)
  f16*   Wf16   = (f16*)(ws + 3 * 16777216);

  // 0) preconvert weights to fp16
  wcvt_kernel<<<dim3(256, 3), 256, 0, stream>>>(Wq, Wk, Wv, Wf16);
  // 1) fused q/k/v projections -> fp16 (S,B,DH) flat
  proj_kernel<<<dim3(128, 1, 3), 512, 0, stream>>>(q, k, v, Wf16, bq, bk, bv,
                                                   qt, kt, vt);
  // 2) logits[b,d,e] = sum_s q_[b,d,s] k_[b,s,e]  (+mask), BM=64 -> 256 blocks
  gemm_tn2_kernel<0, 2><<<dim3(4, 8, 8), 256, 0, stream>>>(
      qt, 1048576L, 2048, kt, 1048576L, 512, 2048, mask, logits, 262144L, 512);
  // 3) P = softmax(logits) over e, fp16
  softmax_kernel<<<dim3(1024), 256, 0, stream>>>(logits, P);
  // 4) out[b,d,s] = sum_e P[b,d,e] v_[b,e,s] -> f32 d_out, BM=128 -> 512 blocks
  gemm_tn2_kernel<1, 4><<<dim3(16, 4, 8), 256, 0, stream>>>(
      P, 262144L, 512, vt, 1048576L, 2048, 512, nullptr, (float*)d_out, 1048576L, 2048);
}

// Round 14
// 149.932 us; speedup vs baseline: 1.0758x; 1.0758x over previous
//
#include <hip/hip_runtime.h>
#include <stdint.h>

typedef _Float16 f16;
typedef __attribute__((ext_vector_type(8))) _Float16 f16x8;
typedef __attribute__((ext_vector_type(4))) float f32x4;
typedef __attribute__((ext_vector_type(2))) unsigned int u32x2;
typedef __attribute__((ext_vector_type(4))) unsigned int u32x4;
typedef decltype(__builtin_amdgcn_cvt_pkrtz(0.f, 0.f)) h2_t;

#define S_LEN 2048
#define BATCH 8
#define D_IN  1024
#define DHALF 512

__device__ __forceinline__ unsigned lds_off(const void* p) {
  return (unsigned)(size_t)p;
}

// async global->LDS DMA, 16B per lane (dest = wave-uniform base + lane*16 by HW)
__device__ __forceinline__ void dma16(const void* g, void* lds_uniform) {
  __builtin_amdgcn_global_load_lds(
      (const __attribute__((address_space(1))) void*)g,
      (__attribute__((address_space(3))) void*)lds_uniform, 16, 0, 0);
}

// ---------------------------------------------------------------------------
// W f32 -> f16 preconvert (one-shot, ~3MB): out[z] = (f16)W[z], layout [n][k].
// ---------------------------------------------------------------------------
__global__ __launch_bounds__(256) void wcvt_kernel(
    const float* __restrict__ Wq, const float* __restrict__ Wk, const float* __restrict__ Wv,
    f16* __restrict__ out)
{
  const int z = blockIdx.y;
  const float* W = (z == 0) ? Wq : (z == 1) ? Wk : Wv;
  const int idx = (blockIdx.x * 256 + threadIdx.x) * 8;
  f32x4 a = *(const f32x4*)(W + idx);
  f32x4 b = *(const f32x4*)(W + idx + 4);
  union { h2_t h2[4]; f16x8 v; } u;
  u.h2[0] = __builtin_amdgcn_cvt_pkrtz(a.x, a.y);
  u.h2[1] = __builtin_amdgcn_cvt_pkrtz(a.z, a.w);
  u.h2[2] = __builtin_amdgcn_cvt_pkrtz(b.x, b.y);
  u.h2[3] = __builtin_amdgcn_cvt_pkrtz(b.z, b.w);
  *(f16x8*)(out + (size_t)z * (DHALF * D_IN) + idx) = u.v;
}

// ---------------------------------------------------------------------------
// Projection v7 = r10 champion structure with BM 128 -> 64.
// out[s,b,e] = sum_d X[s,b,d]*W[e,d] + bias[e], fp16.
// BM=64 x BN=512, 8 waves, wave-tile 64m x 64n (acc[4][4]).
// Why BM=64: r10's 384 blocks @ 1 block/CU ran 2 scheduling rounds
// (256+128 -> half-chip idle in round 2, ~25% waste) and 8 waves/CU capped
// A-path MLP. Now: 768 blocks @ 2 blocks/CU (LDS 80KB x2 = 160KB exact),
// 16 waves/CU, tail smoothed by co-residency.
// A: once-chip-wide 256B NT runs -> reg -> cvt f16 -> XOR-swizzled LDS
//    [64 rows][128B], dbuf, ONE raw barrier per kc64.
// B: wave-local rows [w*64,+64) via global_load_lds (pre-swizzled source),
//    per-wave counted vmcnt (no barrier for B).
// ---------------------------------------------------------------------------
__global__ __launch_bounds__(512, 4) void proj_kernel(
    const float* __restrict__ Xq, const float* __restrict__ Xk, const float* __restrict__ Xv,
    const f16* __restrict__ Wf16,
    const float* __restrict__ bq, const float* __restrict__ bk, const float* __restrict__ bv,
    f16* __restrict__ oq, f16* __restrict__ ok, f16* __restrict__ ov)
{
  const int z = blockIdx.z;
  const float* X    = (z == 0) ? Xq : (z == 1) ? Xk : Xv;
  const f16*   W    = Wf16 + (size_t)z * (DHALF * D_IN);
  const float* bias = (z == 0) ? bq : (z == 1) ? bk : bv;
  f16* out          = (z == 0) ? oq : (z == 1) ? ok : ov;

  const int m0 = blockIdx.x * 64;
  const int tid = threadIdx.x;
  const int lane = tid & 63;
  const int w = tid >> 6;               // wave 0..7 = n-column group (64 cols)
  const int rl = lane & 15, g = lane >> 4;

  __shared__ char Ab[2][8192];          // [64 rows][128B k] f16, XOR-swizzled
  __shared__ char Bb[65536];            // [512 rows][128B k] f16, wave-local 1/8ths

  f32x4 acc[4][4];
#pragma unroll
  for (int i = 0; i < 4; i++)
#pragma unroll
    for (int j = 0; j < 4; j++) acc[i][j] = (f32x4){0.f, 0.f, 0.f, 0.f};

  // A-load: instr i covers rows [w*8 + i*4, +4), 256B run per row (16Bx16 lanes)
  const int arow0 = w * 8 + (lane >> 4);
  const char* gA = (const char*)X + (size_t)(m0 + arow0) * (D_IN * 4) + (lane & 15) * 16;
  const unsigned awkb = (unsigned)(lane & 15) * 8;

  // B-DMA: instr i covers rows [w*64+i*8, +8), 128B per row; source pre-swizzled
  const int brow0 = w * 64 + (lane >> 3);
  const char* gBs = (const char*)W + (size_t)brow0 * (D_IN * 2)
                    + ((((unsigned)(lane & 7)) * 16) ^ (((unsigned)(lane >> 3)) << 4));
  const unsigned bdst0 = (unsigned)w * 8192;

  f32x4 aS[2];

#define LOAD_A(KC) {                                                          \
  _Pragma("unroll")                                                           \
  for (int i = 0; i < 2; i++)                                                 \
    aS[i] = __builtin_nontemporal_load(                                       \
        (const f32x4*)(gA + (size_t)i * 4 * (D_IN * 4) + (size_t)(KC) * 256)); }

#define WRITE_A(BUF) {                                                        \
  _Pragma("unroll")                                                           \
  for (int i = 0; i < 2; i++) {                                               \
    int row = arow0 + i * 4;                                                  \
    union { h2_t h[2]; u32x2 u; } d;                                          \
    d.h[0] = __builtin_amdgcn_cvt_pkrtz(aS[i].x, aS[i].y);                    \
    d.h[1] = __builtin_amdgcn_cvt_pkrtz(aS[i].z, aS[i].w);                    \
    *(u32x2*)(&Ab[BUF][0] + (unsigned)row * 128 +                             \
              (awkb ^ (((unsigned)(row & 7)) << 4))) = d.u;                   \
  } }

#define DMA_B(KC) {                                                           \
  _Pragma("unroll")                                                           \
  for (int i = 0; i < 8; i++)                                                 \
    dma16(gBs + (size_t)i * 8 * (D_IN * 2) + (size_t)(KC) * 128,              \
          &Bb[0] + bdst0 + (unsigned)i * 1024u); }

#define KSTEP(BUF, KS) {                                                      \
  f16x8 bf[4];                                                                \
  _Pragma("unroll")                                                           \
  for (int nf = 0; nf < 4; nf++) {                                            \
    unsigned nrow = (unsigned)(w * 64 + nf * 16 + rl);                        \
    bf[nf] = *(const f16x8*)(&Bb[0] + nrow * 128 +                            \
             ((unsigned)((KS) * 64 + g * 16) ^ (((unsigned)(rl & 7)) << 4))); \
  }                                                                           \
  _Pragma("unroll")                                                           \
  for (int m = 0; m < 4; m++) {                                               \
    unsigned arow = (unsigned)(m * 16 + rl);                                  \
    f16x8 af = *(const f16x8*)(&Ab[BUF][0] + arow * 128 +                     \
             ((unsigned)((KS) * 64 + g * 16) ^ (((unsigned)(rl & 7)) << 4))); \
    _Pragma("unroll")                                                         \
    for (int nf = 0; nf < 4; nf++)                                            \
      acc[m][nf] = __builtin_amdgcn_mfma_f32_16x16x32_f16(                    \
          af, bf[nf], acc[m][nf], 0, 0, 0);                                   \
  } }

  // prologue
  LOAD_A(0);
  WRITE_A(0);                 // compiler waits the 2 A-loads (SSA)
  DMA_B(0);                   // 8 wave-local DMAs
  LOAD_A(1);                  // 2 more in flight
  asm volatile("s_waitcnt lgkmcnt(0)" ::: "memory");
  __builtin_amdgcn_s_barrier();                         // Ab[0] visible
  asm volatile("s_waitcnt vmcnt(2)" ::: "memory");      // B(0) landed; A(1) flying
  __builtin_amdgcn_sched_barrier(0);

  int cur = 0;
  for (int kc = 0; kc < 16; ++kc) {
    KSTEP(cur, 0);
    KSTEP(cur, 1);
    if (kc < 15) {
      WRITE_A(cur ^ 1);       // waits aS(kc+1) loads; other buffer -> race-free
      asm volatile("s_waitcnt lgkmcnt(0)" ::: "memory");
      __builtin_amdgcn_s_barrier();                     // Ab(kc+1) visible to all
      DMA_B(kc + 1);          // overwrite own Bb rows (own reads already consumed)
      if (kc < 14) {
        LOAD_A(kc + 2);
        asm volatile("s_waitcnt vmcnt(2)" ::: "memory"); // B(kc+1) done, A flying
      } else {
        asm volatile("s_waitcnt vmcnt(0)" ::: "memory");
      }
      __builtin_amdgcn_sched_barrier(0);
      cur ^= 1;
    }
  }
#undef LOAD_A
#undef WRITE_A
#undef DMA_B
#undef KSTEP

  // epilogue: + bias, cast fp16; C/D: col = lane&15, row = (lane>>4)*4 + r
#pragma unroll
  for (int m = 0; m < 4; m++) {
    const int row = m0 + m * 16 + g * 4;
#pragma unroll
    for (int nf = 0; nf < 4; nf++) {
      const int col = w * 64 + nf * 16 + rl;
      const float bb = bias[col];
#pragma unroll
      for (int r = 0; r < 4; r++)
        out[(size_t)(row + r) * DHALF + col] = (f16)(acc[m][nf][r] + bb);
    }
  }
}

// ---------------------------------------------------------------------------
// Batched GEMM-TN v2 (r11, unchanged): all staging via global_load_lds with
// pre-swizzled sources; triple buffer, counted vmcnt depth-2.
// ---------------------------------------------------------------------------
template <int EPI, int MI>
__global__ __launch_bounds__(256, 3) void gemm_tn2_kernel(
    const f16* __restrict__ A, long batchA, int lda,
    const f16* __restrict__ Bm, long batchB, int ldb,
    int Ksize,
    const int* __restrict__ mask,
    float* __restrict__ out, long batchOut, int ldo)
{
  constexpr int BM  = MI * 32;
  constexpr int NA  = BM / 64;
  constexpr int ASZ = BM * 64;
  constexpr int SSZ = ASZ + 8192;

  const int bz = blockIdx.z;
  const int n0 = blockIdx.x * 128;
  const int m0 = blockIdx.y * BM;
  const char* Abase = (const char*)(A + (size_t)bz * batchA);
  const char* Bbase = (const char*)(Bm + (size_t)bz * batchB);

  const int tid = threadIdx.x, lane = tid & 63, wave = tid >> 6;
  const int wr = wave >> 1, wc = wave & 1;
  const int g = lane >> 4, rl = lane & 15;

  __shared__ char Buf[3][SSZ];

  f32x4 acc[MI][4];
#pragma unroll
  for (int i = 0; i < MI; i++)
#pragma unroll
    for (int j = 0; j < 4; j++) acc[i][j] = (f32x4){0.f, 0.f, 0.f, 0.f};

  const char* gAsrc[NA];
  unsigned    ldsA[NA];
#pragma unroll
  for (int i = 0; i < NA; i++) {
    int row = wave * (BM / 4) + i * 16 + (lane >> 2);
    unsigned kbyte = (((unsigned)(lane & 3)) * 16) ^ ((((unsigned)lane >> 3) & 3u) << 4);
    gAsrc[i] = Abase + (size_t)(m0 + row) * lda * 2 + kbyte;
    ldsA[i]  = (unsigned)(wave * (BM / 4) + i * 16) * 64;
  }
  const char* gBsrc[2];
  unsigned    ldsB[2];
#pragma unroll
  for (int i = 0; i < 2; i++) {
    int nb   = wave * 2 + i;
    int phys = lane >> 3;
    int kb   = (phys & 3) * 2 + (phys >> 2);
    int kk   = kb * 4 + ((lane >> 1) & 3);
    int nn   = nb * 16 + (lane & 1) * 8;
    gBsrc[i] = Bbase + (size_t)kk * ldb * 2 + (size_t)(n0 + nn) * 2;
    ldsB[i]  = (unsigned)(ASZ + nb * 1024);
  }

#define ISSUE(BUF, STEP) {                                                    \
  _Pragma("unroll")                                                           \
  for (int i = 0; i < NA; i++)                                                \
    dma16(gAsrc[i] + (size_t)(STEP) * 64, &Buf[BUF][0] + ldsA[i]);            \
  _Pragma("unroll")                                                           \
  for (int i = 0; i < 2; i++)                                                 \
    dma16(gBsrc[i] + (size_t)(STEP) * 32 * ldb * 2, &Buf[BUF][0] + ldsB[i]); }

#define COMPUTE(BUF) {                                                        \
  f16x8 af[MI];                                                               \
  _Pragma("unroll")                                                           \
  for (int i = 0; i < MI; i++) {                                              \
    unsigned row  = (unsigned)(wr * (MI * 16) + i * 16 + rl);                 \
    unsigned byte = ((unsigned)(g * 16)) ^ ((((unsigned)rl >> 1) & 3u) << 4); \
    af[i] = *(const f16x8*)(&Buf[BUF][0] + row * 64 + byte);                  \
  }                                                                           \
  f16x8 bf[4];                                                                \
  _Pragma("unroll")                                                           \
  for (int j = 0; j < 4; j++) {                                               \
    unsigned addr = lds_off(&Buf[BUF][0]) + (unsigned)ASZ +                   \
                    (unsigned)((wc * 4 + j) * 1024) + (unsigned)lane * 8u;    \
    u32x2 lo, hi;                                                             \
    asm volatile("ds_read_b64_tr_b16 %0, %1" : "=v"(lo) : "v"(addr));         \
    asm volatile("ds_read_b64_tr_b16 %0, %1 offset:512" : "=v"(hi) : "v"(addr)); \
    union { u32x4 u; f16x8 h; } cc;                                           \
    cc.u = (u32x4){lo.x, lo.y, hi.x, hi.y};                                   \
    bf[j] = cc.h;                                                             \
  }                                                                           \
  asm volatile("s_waitcnt lgkmcnt(0)" ::: "memory");                          \
  __builtin_amdgcn_sched_barrier(0);                                          \
  _Pragma("unroll")                                                           \
  for (int i = 0; i < MI; i++)                                                \
    _Pragma("unroll")                                                         \
    for (int j = 0; j < 4; j++)                                               \
      acc[i][j] = __builtin_amdgcn_mfma_f32_16x16x32_f16(af[i], bf[j], acc[i][j], 0, 0, 0); }

  const int NK = Ksize >> 5;
  ISSUE(0, 0);
  ISSUE(1, 1);

  int cb = 0, ib = 2;
  for (int k = 0; k < NK; ++k) {
    if (k + 1 < NK) {
      if (MI == 2) { asm volatile("s_waitcnt vmcnt(3)" ::: "memory"); }
      else         { asm volatile("s_waitcnt vmcnt(4)" ::: "memory"); }
    } else {
      asm volatile("s_waitcnt vmcnt(0)" ::: "memory");
    }
    __builtin_amdgcn_s_barrier();
    __builtin_amdgcn_sched_barrier(0);
    if (k + 2 < NK) {
      ISSUE(ib, k + 2);
      ib = (ib == 2) ? 0 : ib + 1;
    }
    COMPUTE(cb);
    cb = (cb == 2) ? 0 : cb + 1;
  }
#undef ISSUE
#undef COMPUTE

  float* ob = out + (size_t)bz * batchOut;
#pragma unroll
  for (int i = 0; i < MI; i++) {
    const int row = m0 + wr * (MI * 16) + i * 16 + g * 4;
#pragma unroll
    for (int j = 0; j < 4; j++) {
      const int col = n0 + wc * 64 + j * 16 + rl;
#pragma unroll
      for (int r = 0; r < 4; r++) {
        float val = acc[i][j][r];
        if (EPI == 0) {
          if (mask[(row + r) * DHALF + col] != 0) val = -1e30f;
        }
        ob[(size_t)(row + r) * ldo + col] = val;
      }
    }
  }
}

// ---------------------------------------------------------------------------
// Row softmax over e (512) for 4096 rows; one wave per row; fp16 output.
// ---------------------------------------------------------------------------
__global__ __launch_bounds__(256) void softmax_kernel(
    const float* __restrict__ logits, f16* __restrict__ P)
{
  const int row  = blockIdx.x * 4 + (threadIdx.x >> 6);
  const int lane = threadIdx.x & 63;
  const float* rp = logits + (size_t)row * DHALF + lane * 8;
  f32x4 x0 = *(const f32x4*)rp;
  f32x4 x1 = *(const f32x4*)(rp + 4);

  float m = fmaxf(fmaxf(fmaxf(x0.x, x0.y), fmaxf(x0.z, x0.w)),
                  fmaxf(fmaxf(x1.x, x1.y), fmaxf(x1.z, x1.w)));
#pragma unroll
  for (int off = 32; off > 0; off >>= 1) m = fmaxf(m, __shfl_xor(m, off, 64));

  float e0 = __expf(x0.x - m), e1 = __expf(x0.y - m);
  float e2 = __expf(x0.z - m), e3 = __expf(x0.w - m);
  float e4 = __expf(x1.x - m), e5 = __expf(x1.y - m);
  float e6 = __expf(x1.z - m), e7 = __expf(x1.w - m);
  float s = ((e0 + e1) + (e2 + e3)) + ((e4 + e5) + (e6 + e7));
#pragma unroll
  for (int off = 32; off > 0; off >>= 1) s += __shfl_xor(s, off, 64);
  const float inv = 1.0f / s;

  union { h2_t h2[4]; f16x8 v; } o;
  o.h2[0] = __builtin_amdgcn_cvt_pkrtz(e0 * inv, e1 * inv);
  o.h2[1] = __builtin_amdgcn_cvt_pkrtz(e2 * inv, e3 * inv);
  o.h2[2] = __builtin_amdgcn_cvt_pkrtz(e4 * inv, e5 * inv);
  o.h2[3] = __builtin_amdgcn_cvt_pkrtz(e6 * inv, e7 * inv);
  *(f16x8*)(P + (size_t)row * DHALF + lane * 8) = o.v;
}

// ---------------------------------------------------------------------------
extern "C" void kernel_launch(void* const* d_in, const int* in_sizes, int n_in,
                              void* d_out, int out_size, void* d_ws, size_t ws_size,
                              hipStream_t stream) {
  const float* q    = (const float*)d_in[0];
  const float* k    = (const float*)d_in[1];
  const float* v    = (const float*)d_in[2];
  const int*   mask = (const int*)d_in[3];
  const float* Wq   = (const float*)d_in[4];
  const float* bq   = (const float*)d_in[5];
  const float* Wk   = (const float*)d_in[6];
  const float* bk   = (const float*)d_in[7];
  const float* Wv   = (const float*)d_in[8];
  const float* bv   = (const float*)d_in[9];

  char* ws = (char*)d_ws;
  f16*   qt     = (f16*)(ws);                                  // 16 MB
  f16*   kt     = (f16*)(ws + 16777216);                       // 16 MB
  f16*   vt     = (f16*)(ws + 2 * 16777216);                   // 16 MB
  float* logits = (float*)(ws + 3 * 16777216);                 // 8 MB
  f16*   P      = (f16*)(ws + 3 * 16777216 + 8388608);         // 4 MB
  // Wf16 (3 MB) overlaps the logits region (consumed before QK writes logits)
  f16*   Wf16   = (f16*)(ws + 3 * 16777216);

  // 0) preconvert weights to fp16
  wcvt_kernel<<<dim3(256, 3), 256, 0, stream>>>(Wq, Wk, Wv, Wf16);
  // 1) fused q/k/v projections -> fp16 (S,B,DH) flat; BM=64, 768 blocks, 2/CU
  proj_kernel<<<dim3(256, 1, 3), 512, 0, stream>>>(q, k, v, Wf16, bq, bk, bv,
                                                   qt, kt, vt);
  // 2) logits[b,d,e] = sum_s q_[b,d,s] k_[b,s,e]  (+mask), BM=64 -> 256 blocks
  gemm_tn2_kernel<0, 2><<<dim3(4, 8, 8), 256, 0, stream>>>(
      qt, 1048576L, 2048, kt, 1048576L, 512, 2048, mask, logits, 262144L, 512);
  // 3) P = softmax(logits) over e, fp16
  softmax_kernel<<<dim3(1024), 256, 0, stream>>>(logits, P);
  // 4) out[b,d,s] = sum_e P[b,d,e] v_[b,e,s] -> f32 d_out, BM=128 -> 512 blocks
  gemm_tn2_kernel<1, 4><<<dim3(16, 4, 8), 256, 0, stream>>>(
      P, 262144L, 512, vt, 1048576L, 2048, 512, nullptr, (float*)d_out, 1048576L, 2048);
}

// Round 15
// 140.093 us; speedup vs baseline: 1.1514x; 1.0702x over previous
//
#include <hip/hip_runtime.h>
#include <stdint.h>

typedef _Float16 f16;
typedef __attribute__((ext_vector_type(8))) _Float16 f16x8;
typedef __attribute__((ext_vector_type(4))) float f32x4;
typedef __attribute__((ext_vector_type(2))) unsigned int u32x2;
typedef __attribute__((ext_vector_type(4))) unsigned int u32x4;
typedef decltype(__builtin_amdgcn_cvt_pkrtz(0.f, 0.f)) h2_t;

#define S_LEN 2048
#define BATCH 8
#define D_IN  1024
#define DHALF 512

__device__ __forceinline__ unsigned lds_off(const void* p) {
  return (unsigned)(size_t)p;
}

// async global->LDS DMA, 16B per lane (dest = wave-uniform base + lane*16 by HW)
__device__ __forceinline__ void dma16(const void* g, void* lds_uniform) {
  __builtin_amdgcn_global_load_lds(
      (const __attribute__((address_space(1))) void*)g,
      (__attribute__((address_space(3))) void*)lds_uniform, 16, 0, 0);
}

// ---------------------------------------------------------------------------
// W f32 -> f16 preconvert (one-shot, ~3MB): out[z] = (f16)W[z], layout [n][k].
// ---------------------------------------------------------------------------
__global__ __launch_bounds__(256) void wcvt_kernel(
    const float* __restrict__ Wq, const float* __restrict__ Wk, const float* __restrict__ Wv,
    f16* __restrict__ out)
{
  const int z = blockIdx.y;
  const float* W = (z == 0) ? Wq : (z == 1) ? Wk : Wv;
  const int idx = (blockIdx.x * 256 + threadIdx.x) * 8;
  f32x4 a = *(const f32x4*)(W + idx);
  f32x4 b = *(const f32x4*)(W + idx + 4);
  union { h2_t h2[4]; f16x8 v; } u;
  u.h2[0] = __builtin_amdgcn_cvt_pkrtz(a.x, a.y);
  u.h2[1] = __builtin_amdgcn_cvt_pkrtz(a.z, a.w);
  u.h2[2] = __builtin_amdgcn_cvt_pkrtz(b.x, b.y);
  u.h2[3] = __builtin_amdgcn_cvt_pkrtz(b.z, b.w);
  *(f16x8*)(out + (size_t)z * (DHALF * D_IN) + idx) = u.v;
}

// ---------------------------------------------------------------------------
// Projection v8 = r10 champion (BM=128 x BN=512, 8 waves, 128m x 64n/wave)
// with ONE change: the exposed B drain is removed.
//   OLD per kc: ... barrier -> DMA_B(kc+1) -> LOAD_A -> vmcnt  (B latency
//               serially exposed every kc)
//   NEW per kc: bf reads (both ks) -> lgkmcnt(0) -> DMA_B(kc+1) issued EARLY
//               -> KSTEP0/1 MFMA -> WRITE_A -> barrier -> LOAD_A(kc+2)
//               -> vmcnt(4)   (B covered by ~whole kc of compute)
// Wave-local B rows make the early overwrite-issue race-free (bf in regs).
// A path unchanged: once-chip-wide 256B NT runs -> reg -> cvt f16 ->
// XOR-swizzled LDS [128][128B], dbuf, ONE raw barrier per kc64. LDS 96KB.
// ---------------------------------------------------------------------------
__global__ __launch_bounds__(512, 1) void proj_kernel(
    const float* __restrict__ Xq, const float* __restrict__ Xk, const float* __restrict__ Xv,
    const f16* __restrict__ Wf16,
    const float* __restrict__ bq, const float* __restrict__ bk, const float* __restrict__ bv,
    f16* __restrict__ oq, f16* __restrict__ ok, f16* __restrict__ ov)
{
  const int z = blockIdx.z;
  const float* X    = (z == 0) ? Xq : (z == 1) ? Xk : Xv;
  const f16*   W    = Wf16 + (size_t)z * (DHALF * D_IN);
  const float* bias = (z == 0) ? bq : (z == 1) ? bk : bv;
  f16* out          = (z == 0) ? oq : (z == 1) ? ok : ov;

  const int m0 = blockIdx.x * 128;
  const int tid = threadIdx.x;
  const int lane = tid & 63;
  const int w = tid >> 6;               // wave 0..7 = n-column group (64 cols)
  const int rl = lane & 15, g = lane >> 4;

  __shared__ char Ab[2][16384];         // [128 rows][128B k] f16, XOR-swizzled
  __shared__ char Bb[65536];            // [512 rows][128B k] f16, wave-local 1/8ths

  f32x4 acc[8][4];
#pragma unroll
  for (int i = 0; i < 8; i++)
#pragma unroll
    for (int j = 0; j < 4; j++) acc[i][j] = (f32x4){0.f, 0.f, 0.f, 0.f};

  // A-load: instr i covers rows [w*16+i*4, +4), 256B run per row (16B x 16 lanes)
  const int arow0 = w * 16 + (lane >> 4);
  const char* gA = (const char*)X + (size_t)(m0 + arow0) * (D_IN * 4) + (lane & 15) * 16;
  const unsigned awkb = (unsigned)(lane & 15) * 8;

  // B-DMA: instr i covers rows [w*64+i*8, +8), 128B per row; source pre-swizzled
  const int brow0 = w * 64 + (lane >> 3);
  const char* gBs = (const char*)W + (size_t)brow0 * (D_IN * 2)
                    + ((((unsigned)(lane & 7)) * 16) ^ (((unsigned)(lane >> 3)) << 4));
  const unsigned bdst0 = (unsigned)w * 8192;

  f32x4 aS[4];

#define LOAD_A(KC) {                                                          \
  _Pragma("unroll")                                                           \
  for (int i = 0; i < 4; i++)                                                 \
    aS[i] = __builtin_nontemporal_load(                                       \
        (const f32x4*)(gA + (size_t)i * 4 * (D_IN * 4) + (size_t)(KC) * 256)); }

#define WRITE_A(BUF) {                                                        \
  _Pragma("unroll")                                                           \
  for (int i = 0; i < 4; i++) {                                               \
    int row = arow0 + i * 4;                                                  \
    union { h2_t h[2]; u32x2 u; } d;                                          \
    d.h[0] = __builtin_amdgcn_cvt_pkrtz(aS[i].x, aS[i].y);                    \
    d.h[1] = __builtin_amdgcn_cvt_pkrtz(aS[i].z, aS[i].w);                    \
    *(u32x2*)(&Ab[BUF][0] + (unsigned)row * 128 +                             \
              (awkb ^ (((unsigned)(row & 7)) << 4))) = d.u;                   \
  } }

#define DMA_B(KC) {                                                           \
  _Pragma("unroll")                                                           \
  for (int i = 0; i < 8; i++)                                                 \
    dma16(gBs + (size_t)i * 8 * (D_IN * 2) + (size_t)(KC) * 128,              \
          &Bb[0] + bdst0 + (unsigned)i * 1024u); }

// af reads + MFMA only (bf supplied in registers)
#define KSTEP_AF(BUF, KS, BF) {                                               \
  _Pragma("unroll")                                                           \
  for (int m = 0; m < 8; m++) {                                               \
    unsigned arow = (unsigned)(m * 16 + rl);                                  \
    f16x8 af = *(const f16x8*)(&Ab[BUF][0] + arow * 128 +                     \
             ((unsigned)((KS) * 64 + g * 16) ^ (((unsigned)(rl & 7)) << 4))); \
    _Pragma("unroll")                                                         \
    for (int nf = 0; nf < 4; nf++)                                            \
      acc[m][nf] = __builtin_amdgcn_mfma_f32_16x16x32_f16(                    \
          af, BF[nf], acc[m][nf], 0, 0, 0);                                   \
  } }

  // prologue
  LOAD_A(0);
  WRITE_A(0);                 // compiler waits the 4 A-loads (SSA)
  DMA_B(0);                   // 8 wave-local DMAs
  LOAD_A(1);                  // 4 more in flight
  asm volatile("s_waitcnt lgkmcnt(0)" ::: "memory");
  __builtin_amdgcn_s_barrier();                         // Ab[0] visible
  asm volatile("s_waitcnt vmcnt(4)" ::: "memory");      // B(0) landed; A(1) flying
  __builtin_amdgcn_sched_barrier(0);

  int cur = 0;
  for (int kc = 0; kc < 16; ++kc) {
    // 1) ALL bf reads for this kc (both ks), retire into registers
    f16x8 bf0[4], bf1[4];
#pragma unroll
    for (int nf = 0; nf < 4; nf++) {
      unsigned nrow = (unsigned)(w * 64 + nf * 16 + rl);
      unsigned swz  = ((unsigned)(rl & 7)) << 4;
      bf0[nf] = *(const f16x8*)(&Bb[0] + nrow * 128 + (((unsigned)(g * 16)) ^ swz));
      bf1[nf] = *(const f16x8*)(&Bb[0] + nrow * 128 + (((unsigned)(64 + g * 16)) ^ swz));
    }
    asm volatile("s_waitcnt lgkmcnt(0)" ::: "memory");  // bf in regs
    __builtin_amdgcn_sched_barrier(0);

    // 2) issue next-kc B EARLY (wave-local rows; covered by the rest of kc)
    if (kc < 15) { DMA_B(kc + 1); }

    // 3) compute
    KSTEP_AF(cur, 0, bf0);
    KSTEP_AF(cur, 1, bf1);

    if (kc < 15) {
      WRITE_A(cur ^ 1);       // compiler waits A(kc+1) regs (vmcnt leaves B flying)
      asm volatile("s_waitcnt lgkmcnt(0)" ::: "memory");
      __builtin_amdgcn_s_barrier();                     // Ab(kc+1) visible to all
      if (kc < 14) {
        LOAD_A(kc + 2);
        asm volatile("s_waitcnt vmcnt(4)" ::: "memory"); // B(kc+1) done, A flying
      } else {
        asm volatile("s_waitcnt vmcnt(0)" ::: "memory");
      }
      __builtin_amdgcn_sched_barrier(0);
      cur ^= 1;
    }
  }
#undef LOAD_A
#undef WRITE_A
#undef DMA_B
#undef KSTEP_AF

  // epilogue: + bias, cast fp16; C/D: col = lane&15, row = (lane>>4)*4 + r
#pragma unroll
  for (int m = 0; m < 8; m++) {
    const int row = m0 + m * 16 + g * 4;
#pragma unroll
    for (int nf = 0; nf < 4; nf++) {
      const int col = w * 64 + nf * 16 + rl;
      const float bb = bias[col];
#pragma unroll
      for (int r = 0; r < 4; r++)
        out[(size_t)(row + r) * DHALF + col] = (f16)(acc[m][nf][r] + bb);
    }
  }
}

// ---------------------------------------------------------------------------
// Batched GEMM-TN v2 (r11, unchanged): all staging via global_load_lds with
// pre-swizzled sources; triple buffer, counted vmcnt depth-2.
// ---------------------------------------------------------------------------
template <int EPI, int MI>
__global__ __launch_bounds__(256, 3) void gemm_tn2_kernel(
    const f16* __restrict__ A, long batchA, int lda,
    const f16* __restrict__ Bm, long batchB, int ldb,
    int Ksize,
    const int* __restrict__ mask,
    float* __restrict__ out, long batchOut, int ldo)
{
  constexpr int BM  = MI * 32;
  constexpr int NA  = BM / 64;
  constexpr int ASZ = BM * 64;
  constexpr int SSZ = ASZ + 8192;

  const int bz = blockIdx.z;
  const int n0 = blockIdx.x * 128;
  const int m0 = blockIdx.y * BM;
  const char* Abase = (const char*)(A + (size_t)bz * batchA);
  const char* Bbase = (const char*)(Bm + (size_t)bz * batchB);

  const int tid = threadIdx.x, lane = tid & 63, wave = tid >> 6;
  const int wr = wave >> 1, wc = wave & 1;
  const int g = lane >> 4, rl = lane & 15;

  __shared__ char Buf[3][SSZ];

  f32x4 acc[MI][4];
#pragma unroll
  for (int i = 0; i < MI; i++)
#pragma unroll
    for (int j = 0; j < 4; j++) acc[i][j] = (f32x4){0.f, 0.f, 0.f, 0.f};

  const char* gAsrc[NA];
  unsigned    ldsA[NA];
#pragma unroll
  for (int i = 0; i < NA; i++) {
    int row = wave * (BM / 4) + i * 16 + (lane >> 2);
    unsigned kbyte = (((unsigned)(lane & 3)) * 16) ^ ((((unsigned)lane >> 3) & 3u) << 4);
    gAsrc[i] = Abase + (size_t)(m0 + row) * lda * 2 + kbyte;
    ldsA[i]  = (unsigned)(wave * (BM / 4) + i * 16) * 64;
  }
  const char* gBsrc[2];
  unsigned    ldsB[2];
#pragma unroll
  for (int i = 0; i < 2; i++) {
    int nb   = wave * 2 + i;
    int phys = lane >> 3;
    int kb   = (phys & 3) * 2 + (phys >> 2);
    int kk   = kb * 4 + ((lane >> 1) & 3);
    int nn   = nb * 16 + (lane & 1) * 8;
    gBsrc[i] = Bbase + (size_t)kk * ldb * 2 + (size_t)(n0 + nn) * 2;
    ldsB[i]  = (unsigned)(ASZ + nb * 1024);
  }

#define ISSUE(BUF, STEP) {                                                    \
  _Pragma("unroll")                                                           \
  for (int i = 0; i < NA; i++)                                                \
    dma16(gAsrc[i] + (size_t)(STEP) * 64, &Buf[BUF][0] + ldsA[i]);            \
  _Pragma("unroll")                                                           \
  for (int i = 0; i < 2; i++)                                                 \
    dma16(gBsrc[i] + (size_t)(STEP) * 32 * ldb * 2, &Buf[BUF][0] + ldsB[i]); }

#define COMPUTE(BUF) {                                                        \
  f16x8 af[MI];                                                               \
  _Pragma("unroll")                                                           \
  for (int i = 0; i < MI; i++) {                                              \
    unsigned row  = (unsigned)(wr * (MI * 16) + i * 16 + rl);                 \
    unsigned byte = ((unsigned)(g * 16)) ^ ((((unsigned)rl >> 1) & 3u) << 4); \
    af[i] = *(const f16x8*)(&Buf[BUF][0] + row * 64 + byte);                  \
  }                                                                           \
  f16x8 bf[4];                                                                \
  _Pragma("unroll")                                                           \
  for (int j = 0; j < 4; j++) {                                               \
    unsigned addr = lds_off(&Buf[BUF][0]) + (unsigned)ASZ +                   \
                    (unsigned)((wc * 4 + j) * 1024) + (unsigned)lane * 8u;    \
    u32x2 lo, hi;                                                             \
    asm volatile("ds_read_b64_tr_b16 %0, %1" : "=v"(lo) : "v"(addr));         \
    asm volatile("ds_read_b64_tr_b16 %0, %1 offset:512" : "=v"(hi) : "v"(addr)); \
    union { u32x4 u; f16x8 h; } cc;                                           \
    cc.u = (u32x4){lo.x, lo.y, hi.x, hi.y};                                   \
    bf[j] = cc.h;                                                             \
  }                                                                           \
  asm volatile("s_waitcnt lgkmcnt(0)" ::: "memory");                          \
  __builtin_amdgcn_sched_barrier(0);                                          \
  _Pragma("unroll")                                                           \
  for (int i = 0; i < MI; i++)                                                \
    _Pragma("unroll")                                                         \
    for (int j = 0; j < 4; j++)                                               \
      acc[i][j] = __builtin_amdgcn_mfma_f32_16x16x32_f16(af[i], bf[j], acc[i][j], 0, 0, 0); }

  const int NK = Ksize >> 5;
  ISSUE(0, 0);
  ISSUE(1, 1);

  int cb = 0, ib = 2;
  for (int k = 0; k < NK; ++k) {
    if (k + 1 < NK) {
      if (MI == 2) { asm volatile("s_waitcnt vmcnt(3)" ::: "memory"); }
      else         { asm volatile("s_waitcnt vmcnt(4)" ::: "memory"); }
    } else {
      asm volatile("s_waitcnt vmcnt(0)" ::: "memory");
    }
    __builtin_amdgcn_s_barrier();
    __builtin_amdgcn_sched_barrier(0);
    if (k + 2 < NK) {
      ISSUE(ib, k + 2);
      ib = (ib == 2) ? 0 : ib + 1;
    }
    COMPUTE(cb);
    cb = (cb == 2) ? 0 : cb + 1;
  }
#undef ISSUE
#undef COMPUTE

  float* ob = out + (size_t)bz * batchOut;
#pragma unroll
  for (int i = 0; i < MI; i++) {
    const int row = m0 + wr * (MI * 16) + i * 16 + g * 4;
#pragma unroll
    for (int j = 0; j < 4; j++) {
      const int col = n0 + wc * 64 + j * 16 + rl;
#pragma unroll
      for (int r = 0; r < 4; r++) {
        float val = acc[i][j][r];
        if (EPI == 0) {
          if (mask[(row + r) * DHALF + col] != 0) val = -1e30f;
        }
        ob[(size_t)(row + r) * ldo + col] = val;
      }
    }
  }
}

// ---------------------------------------------------------------------------
// Row softmax over e (512) for 4096 rows; one wave per row; fp16 output.
// ---------------------------------------------------------------------------
__global__ __launch_bounds__(256) void softmax_kernel(
    const float* __restrict__ logits, f16* __restrict__ P)
{
  const int row  = blockIdx.x * 4 + (threadIdx.x >> 6);
  const int lane = threadIdx.x & 63;
  const float* rp = logits + (size_t)row * DHALF + lane * 8;
  f32x4 x0 = *(const f32x4*)rp;
  f32x4 x1 = *(const f32x4*)(rp + 4);

  float m = fmaxf(fmaxf(fmaxf(x0.x, x0.y), fmaxf(x0.z, x0.w)),
                  fmaxf(fmaxf(x1.x, x1.y), fmaxf(x1.z, x1.w)));
#pragma unroll
  for (int off = 32; off > 0; off >>= 1) m = fmaxf(m, __shfl_xor(m, off, 64));

  float e0 = __expf(x0.x - m), e1 = __expf(x0.y - m);
  float e2 = __expf(x0.z - m), e3 = __expf(x0.w - m);
  float e4 = __expf(x1.x - m), e5 = __expf(x1.y - m);
  float e6 = __expf(x1.z - m), e7 = __expf(x1.w - m);
  float s = ((e0 + e1) + (e2 + e3)) + ((e4 + e5) + (e6 + e7));
#pragma unroll
  for (int off = 32; off > 0; off >>= 1) s += __shfl_xor(s, off, 64);
  const float inv = 1.0f / s;

  union { h2_t h2[4]; f16x8 v; } o;
  o.h2[0] = __builtin_amdgcn_cvt_pkrtz(e0 * inv, e1 * inv);
  o.h2[1] = __builtin_amdgcn_cvt_pkrtz(e2 * inv, e3 * inv);
  o.h2[2] = __builtin_amdgcn_cvt_pkrtz(e4 * inv, e5 * inv);
  o.h2[3] = __builtin_amdgcn_cvt_pkrtz(e6 * inv, e7 * inv);
  *(f16x8*)(P + (size_t)row * DHALF + lane * 8) = o.v;
}

// ---------------------------------------------------------------------------
extern "C" void kernel_launch(void* const* d_in, const int* in_sizes, int n_in,
                              void* d_out, int out_size, void* d_ws, size_t ws_size,
                              hipStream_t stream) {
  const float* q    = (const float*)d_in[0];
  const float* k    = (const float*)d_in[1];
  const float* v    = (const float*)d_in[2];
  const int*   mask = (const int*)d_in[3];
  const float* Wq   = (const float*)d_in[4];
  const float* bq   = (const float*)d_in[5];
  const float* Wk   = (const float*)d_in[6];
  const float* bk   = (const float*)d_in[7];
  const float* Wv   = (const float*)d_in[8];
  const float* bv   = (const float*)d_in[9];

  char* ws = (char*)d_ws;
  f16*   qt     = (f16*)(ws);                                  // 16 MB
  f16*   kt     = (f16*)(ws + 16777216);                       // 16 MB
  f16*   vt     = (f16*)(ws + 2 * 16777216);                   // 16 MB
  float* logits = (float*)(ws + 3 * 16777216);                 // 8 MB
  f16*   P      = (f16*)(ws + 3 * 16777216 + 8388608);         // 4 MB
  // Wf16 (3 MB) overlaps the logits region (consumed before QK writes logits)
  f16*   Wf16   = (f16*)(ws + 3 * 16777216);

  // 0) preconvert weights to fp16
  wcvt_kernel<<<dim3(256, 3), 256, 0, stream>>>(Wq, Wk, Wv, Wf16);
  // 1) fused q/k/v projections -> fp16 (S,B,DH) flat; BM=128, B-issue-early
  proj_kernel<<<dim3(128, 1, 3), 512, 0, stream>>>(q, k, v, Wf16, bq, bk, bv,
                                                   qt, kt, vt);
  // 2) logits[b,d,e] = sum_s q_[b,d,s] k_[b,s,e]  (+mask), BM=64 -> 256 blocks
  gemm_tn2_kernel<0, 2><<<dim3(4, 8, 8), 256, 0, stream>>>(
      qt, 1048576L, 2048, kt, 1048576L, 512, 2048, mask, logits, 262144L, 512);
  // 3) P = softmax(logits) over e, fp16
  softmax_kernel<<<dim3(1024), 256, 0, stream>>>(logits, P);
  // 4) out[b,d,s] = sum_e P[b,d,e] v_[b,e,s] -> f32 d_out, BM=128 -> 512 blocks
  gemm_tn2_kernel<1, 4><<<dim3(16, 4, 8), 256, 0, stream>>>(
      P, 262144L, 512, vt, 1048576L, 2048, 512, nullptr, (float*)d_out, 1048576L, 2048);
}